// Round 2
// baseline (261.138 us; speedup 1.0000x reference)
//
#include <hip/hip_runtime.h>

// AlgebraicAttention on MI355X (gfx950), round 2: minimal-workspace correctness build.
// Crash theory for round 1: ws overflow (assumed 48MB). This round uses only 8MB of ws.
// Layout:
//   ws[0,8M)        : Q bf16 [4096][1024]; overwritten in-place by attention output
//   d_out[0,8M)     : K bf16 [4096][1024]   (scratch; dead before final GEMM writes)
//   d_out[8M,16M)   : V bf16 [4096][1024]
// Pipeline: fused QKV GEMM (fp32 in, inline bf16 cast, MFMA) -> relu-attention (MFMA,
// flash-style, no softmax needed) -> output GEMM (fp32 out to d_out).

typedef __attribute__((ext_vector_type(8))) __bf16 bf16x8;
typedef __attribute__((ext_vector_type(4))) float f32x4;
typedef unsigned short u16;

__device__ __forceinline__ u16 f2bf(float f) {
  unsigned u = __float_as_uint(f);
  u += 0x7FFFu + ((u >> 16) & 1u);   // round-to-nearest-even
  return (u16)(u >> 16);
}
__device__ __forceinline__ float bf2f(u16 b) {
  return __uint_as_float(((unsigned)b) << 16);
}
__device__ __forceinline__ bf16x8 pack8(float4 a, float4 b) {
  union { bf16x8 v; u16 s[8]; } u;
  u.s[0] = f2bf(a.x); u.s[1] = f2bf(a.y); u.s[2] = f2bf(a.z); u.s[3] = f2bf(a.w);
  u.s[4] = f2bf(b.x); u.s[5] = f2bf(b.y); u.s[6] = f2bf(b.z); u.s[7] = f2bf(b.w);
  return u.v;
}

// ---------------------------------------------------------------- GEMM  C = A @ B^T + bias
// A: [M x 1024] (fp32 or bf16 per template) row-major. B: fp32 weight rows [out,in],
// converted to bf16 during LDS staging. 128x128 tile, BK=64, 4 waves in 2x2, each wave
// 64x64 via 4x4 grid of 16x16x32 bf16 MFMA. blockIdx.y selects one of up to 3 outputs
// (8 y-blocks per 1024-wide output) so QKV is a single launch.
template <bool A_BF16, bool STORE_BF16>
__global__ __launch_bounds__(256) void gemm_bt(
    const void* __restrict__ A_,
    const float* __restrict__ B0f, const float* __restrict__ B1f,
    const float* __restrict__ B2f,
    const float* __restrict__ b0, const float* __restrict__ b1,
    const float* __restrict__ b2,
    void* __restrict__ C0, void* __restrict__ C1, void* __restrict__ C2) {
  constexpr int K = 1024;
  __shared__ __align__(16) u16 As[128 * 64];
  __shared__ __align__(16) u16 Bs[128 * 64];

  const int m0 = blockIdx.x * 128;
  const int sel = blockIdx.y >> 3;
  const int nloc = (blockIdx.y & 7) * 128;
  const float* Bf = sel == 0 ? B0f : sel == 1 ? B1f : B2f;
  const float* bias = sel == 0 ? b0 : sel == 1 ? b1 : b2;
  void* Cout = sel == 0 ? C0 : sel == 1 ? C1 : C2;

  const int t = threadIdx.x;
  const int lane = t & 63;
  const int wv = t >> 6;
  const int quad = lane >> 4;
  const int l15 = lane & 15;
  const int wr = wv >> 1, wc = wv & 1;

  const f32x4 vzero = {0.f, 0.f, 0.f, 0.f};
  f32x4 acc[4][4];
#pragma unroll
  for (int i = 0; i < 4; ++i)
#pragma unroll
    for (int j = 0; j < 4; ++j) acc[i][j] = vzero;

  for (int kt = 0; kt < K / 64; ++kt) {
    const int k0 = kt * 64;
#pragma unroll
    for (int p = 0; p < 4; ++p) {
      int idx = t + p * 256;          // 1024 8-element groups per tile
      int row = idx >> 3, c8 = idx & 7;
      if (A_BF16) {
        *(bf16x8*)&As[idx * 8] =
            *(const bf16x8*)&((const u16*)A_)[(long)(m0 + row) * K + k0 + c8 * 8];
      } else {
        const float* A = (const float*)A_;
        float4 a = *(const float4*)&A[(long)(m0 + row) * K + k0 + c8 * 8];
        float4 b = *(const float4*)&A[(long)(m0 + row) * K + k0 + c8 * 8 + 4];
        *(bf16x8*)&As[idx * 8] = pack8(a, b);
      }
      float4 ba = *(const float4*)&Bf[(long)(nloc + row) * K + k0 + c8 * 8];
      float4 bb = *(const float4*)&Bf[(long)(nloc + row) * K + k0 + c8 * 8 + 4];
      *(bf16x8*)&Bs[idx * 8] = pack8(ba, bb);
    }
    __syncthreads();
#pragma unroll
    for (int ks = 0; ks < 64; ks += 32) {
      bf16x8 af[4], bfg[4];
#pragma unroll
      for (int i = 0; i < 4; ++i)
        af[i] = *(const bf16x8*)&As[(wr * 64 + i * 16 + l15) * 64 + ks + quad * 8];
#pragma unroll
      for (int j = 0; j < 4; ++j)
        bfg[j] = *(const bf16x8*)&Bs[(wc * 64 + j * 16 + l15) * 64 + ks + quad * 8];
#pragma unroll
      for (int i = 0; i < 4; ++i)
#pragma unroll
        for (int j = 0; j < 4; ++j)
          acc[i][j] = __builtin_amdgcn_mfma_f32_16x16x32_bf16(af[i], bfg[j], acc[i][j], 0, 0, 0);
    }
    __syncthreads();
  }

  float bv[4];
#pragma unroll
  for (int j = 0; j < 4; ++j) bv[j] = bias[nloc + wc * 64 + j * 16 + l15];

#pragma unroll
  for (int i = 0; i < 4; ++i) {
#pragma unroll
    for (int r = 0; r < 4; ++r) {
      int row = m0 + wr * 64 + i * 16 + quad * 4 + r;
      long base = (long)row * 1024 + nloc + wc * 64;
#pragma unroll
      for (int j = 0; j < 4; ++j) {
        float v = acc[i][j][r] + bv[j];
        if (STORE_BF16) ((u16*)Cout)[base + j * 16 + l15] = f2bf(v);
        else            ((float*)Cout)[base + j * 16 + l15] = v;
      }
    }
  }
}

// ---------------------------------------------------------------- attention
// One block = (b, h, 64 q-rows). 4 waves, wave wv owns q rows q0+wv*16..+15.
// Loop over 64-wide k-chunks (causal: c <= qb). Per chunk:
//   S = Q K^T (MFMA, C-layout: q=quad*4+r, key=lane&15)
//   w = relu(S*scale + rel_bias) + 1e-6, causal-masked; denom accumulated in-register
//   w -> bf16 -> wave-private LDS -> reload in A-layout;  O += W @ V (V staged transposed)
// Epilogue: denom shuffle-reduced across the 16 lanes of each quad; O scaled; bf16 store
// IN-PLACE over this block's own Q region (disjoint across blocks, read-before-write).
__global__ __launch_bounds__(256) void attn_kernel(
    const u16* __restrict__ Qb,     // [4096][1024], also output (att)
    const u16* __restrict__ Kb,     // [4096][1024]
    const u16* __restrict__ Vb,     // [4096][1024]
    const float* __restrict__ rel_bias,  // [63][16]
    u16* __restrict__ att) {
  __shared__ __align__(16) u16 Ks[64 * 64];
  __shared__ __align__(16) u16 Vt[64 * 72];
  __shared__ __align__(16) u16 Ws[4][16 * 64];
  __shared__ float biasl[64];

  const int bx = blockIdx.x;
  const int qb = bx & 15;
  const int bh = bx >> 4;
  const int b = bh >> 4, h = bh & 15;
  const int q0 = qb * 64;

  const int t = threadIdx.x;
  const int lane = t & 63;
  const int wv = t >> 6;
  const int quad = lane >> 4;
  const int l15 = lane & 15;

  if (t < 63) biasl[t] = rel_bias[t * 16 + h];

  // Q fragments for this wave's 16 q-rows (A-layout: row=lane&15, k=quad*8+j)
  const long qrow = (long)(b * 1024 + q0 + wv * 16 + l15) * 1024 + h * 64;
  bf16x8 qf0 = *(const bf16x8*)&Qb[qrow + quad * 8];
  bf16x8 qf1 = *(const bf16x8*)&Qb[qrow + 32 + quad * 8];

  const f32x4 vzero = {0.f, 0.f, 0.f, 0.f};
  f32x4 acc_o[4];
#pragma unroll
  for (int j = 0; j < 4; ++j) acc_o[j] = vzero;
  f32x4 denom = vzero;
  const float scale = 0.125f;  // 64^-0.5
  const int myq = q0 + wv * 16 + quad * 4;

  for (int c = 0; c <= qb; ++c) {
    const int k0 = c * 64;
    if (c) __syncthreads();  // protect Ks/Vt reuse across iterations
    // stage K rows [k0..k0+63] x 64 head-cols (plain vector load + ds write)
#pragma unroll
    for (int p = 0; p < 2; ++p) {
      int idx = t + p * 256;
      int row = idx >> 3, seg = idx & 7;
      *(bf16x8*)&Ks[idx * 8] =
          *(const bf16x8*)&Kb[(long)(b * 1024 + k0 + row) * 1024 + h * 64 + seg * 8];
    }
    // stage V transposed: Vt[d][k] = V[k0+k][h*64+d], row stride 72
#pragma unroll
    for (int p = 0; p < 2; ++p) {
      int seg = lane >> 3;
      int krel = (lane & 7) + (p * 4 + wv) * 8;
      uint4 vvld = *(const uint4*)&Vb[(long)(b * 1024 + k0 + krel) * 1024 + h * 64 + seg * 8];
      const u16* u = (const u16*)&vvld;
#pragma unroll
      for (int j = 0; j < 8; ++j) Vt[(seg * 8 + j) * 72 + krel] = u[j];
    }
    __syncthreads();

    // S tiles + weight transform
#pragma unroll
    for (int g = 0; g < 4; ++g) {
      bf16x8 kf0 = *(const bf16x8*)&Ks[(g * 16 + l15) * 64 + quad * 8];
      bf16x8 kf1 = *(const bf16x8*)&Ks[(g * 16 + l15) * 64 + 32 + quad * 8];
      f32x4 s = vzero;
      s = __builtin_amdgcn_mfma_f32_16x16x32_bf16(qf0, kf0, s, 0, 0, 0);
      s = __builtin_amdgcn_mfma_f32_16x16x32_bf16(qf1, kf1, s, 0, 0, 0);
      const int kg = k0 + g * 16 + l15;
#pragma unroll
      for (int r = 0; r < 4; ++r) {
        int q = myq + r;
        int dd = kg - q;
        dd = dd < -31 ? -31 : (dd > 31 ? 31 : dd);
        float sv = s[r] * scale + biasl[dd + 31];
        float w = (kg <= q) ? (fmaxf(sv, 0.f) + 1e-6f) : 0.f;
        u16 wb = f2bf(w);
        denom[r] += bf2f(wb);  // accumulate exactly what PV will consume
        Ws[wv][(quad * 4 + r) * 64 + g * 16 + l15] = wb;
      }
    }
    // intra-wave LDS write->read ordering (Ws[wv] is wave-private)
    asm volatile("s_waitcnt lgkmcnt(0)" ::: "memory");
    // PV: O[q, d] += W[q, k] * V[k, d]
#pragma unroll
    for (int ks = 0; ks < 64; ks += 32) {
      bf16x8 aw = *(const bf16x8*)&Ws[wv][l15 * 64 + ks + quad * 8];
#pragma unroll
      for (int j = 0; j < 4; ++j) {
        bf16x8 bvv = *(const bf16x8*)&Vt[(j * 16 + l15) * 72 + ks + quad * 8];
        acc_o[j] = __builtin_amdgcn_mfma_f32_16x16x32_bf16(aw, bvv, acc_o[j], 0, 0, 0);
      }
    }
  }

  // denom: sum across the 16 lanes of each quad (key-columns of the C-tile)
#pragma unroll
  for (int m = 1; m < 16; m <<= 1)
#pragma unroll
    for (int r = 0; r < 4; ++r) denom[r] += __shfl_xor(denom[r], m);

  float inv[4];
#pragma unroll
  for (int r = 0; r < 4; ++r) inv[r] = 1.f / (denom[r] + 1e-6f);

#pragma unroll
  for (int j = 0; j < 4; ++j)
#pragma unroll
    for (int r = 0; r < 4; ++r) {
      int q = myq + r;
      att[(long)(b * 1024 + q) * 1024 + h * 64 + j * 16 + l15] = f2bf(acc_o[j][r] * inv[r]);
    }
}

// ---------------------------------------------------------------- launch
extern "C" void kernel_launch(void* const* d_in, const int* in_sizes, int n_in,
                              void* d_out, int out_size, void* d_ws, size_t ws_size,
                              hipStream_t stream) {
  const float* x  = (const float*)d_in[0];
  // d_in[1] = mask (causal tril, known analytically -> unused)
  const float* Wq = (const float*)d_in[2];
  const float* bq = (const float*)d_in[3];
  const float* Wk = (const float*)d_in[4];
  const float* bk = (const float*)d_in[5];
  const float* Wv = (const float*)d_in[6];
  const float* bv = (const float*)d_in[7];
  const float* Wo = (const float*)d_in[8];
  const float* bo = (const float*)d_in[9];
  const float* rb = (const float*)d_in[10];
  // d_in[11] = n_head (constant 16) unused

  u16* Qb = (u16*)d_ws;                          // 8MB in ws; becomes att in-place
  u16* Kb = (u16*)d_out;                         // 8MB scratch inside d_out
  u16* Vb = (u16*)((char*)d_out + (8l << 20));   // 8MB scratch inside d_out

  // QKV projection: one launch, three outputs (sel = blockIdx.y >> 3)
  gemm_bt<false, true><<<dim3(32, 24), 256, 0, stream>>>(
      x, Wq, Wk, Wv, bq, bk, bv, Qb, Kb, Vb);
  // relu-attention; writes att in-place over Qb
  attn_kernel<<<1024, 256, 0, stream>>>(Qb, Kb, Vb, rb, Qb);
  // output projection: reads att (bf16), writes final fp32 d_out (overwrites K/V scratch)
  gemm_bt<true, false><<<dim3(32, 8), 256, 0, stream>>>(
      Qb, Wo, Wo, Wo, bo, bo, bo, d_out, d_out, d_out);
}

// Round 3
// 237.093 us; speedup vs baseline: 1.1014x; 1.1014x over previous
//
#include <hip/hip_runtime.h>

// AlgebraicAttention on MI355X (gfx950), round 3.
// Round-2 post-mortem: QKV GEMM latency-bound at 270 TF (MfmaUtil 10%, VALUBusy 20%,
// Occ 17%) due to fp32 register staging + pack. Fix = guide's m93->m97 step: pre-cast
// inputs to bf16, stage via global_load_lds width=16.
// ws layout (fast path, needs >= 24MB ws; runtime-checked, else round-2 fallback):
//   ws[0,8M)    xb : x as bf16 [4096][1024]
//   ws[8M,16M)  wqb/wkb/wvb/wob : weights bf16, 2MB each
//   ws[16M,24M) Qb : Q bf16 [4096][1024]; overwritten in-place by attention output
//   d_out[0,8M) Kb, d_out[8M,16M) Vb : bf16 scratch (dead before final GEMM writes)

typedef __attribute__((ext_vector_type(8))) __bf16 bf16x8;
typedef __attribute__((ext_vector_type(4))) float f32x4;
typedef unsigned short u16;

__device__ __forceinline__ u16 f2bf(float f) {
  unsigned u = __float_as_uint(f);
  u += 0x7FFFu + ((u >> 16) & 1u);   // round-to-nearest-even
  return (u16)(u >> 16);
}
__device__ __forceinline__ float bf2f(u16 b) {
  return __uint_as_float(((unsigned)b) << 16);
}
__device__ __forceinline__ bf16x8 pack8(float4 a, float4 b) {
  union { bf16x8 v; u16 s[8]; } u;
  u.s[0] = f2bf(a.x); u.s[1] = f2bf(a.y); u.s[2] = f2bf(a.z); u.s[3] = f2bf(a.w);
  u.s[4] = f2bf(b.x); u.s[5] = f2bf(b.y); u.s[6] = f2bf(b.z); u.s[7] = f2bf(b.w);
  return u.v;
}
__device__ __forceinline__ void gl_lds16(const void* g, void* l) {
  __builtin_amdgcn_global_load_lds((__attribute__((address_space(1))) void*)g,
                                   (__attribute__((address_space(3))) void*)l,
                                   16, 0, 0);
}

// ---------------------------------------------------------------- cast kernel
// 8.39M floats (x + 4 weights) -> bf16, float4-vectorized. BW-bound, ~10us.
__global__ __launch_bounds__(256) void cast_all_kernel(
    const float* __restrict__ x,  const float* __restrict__ wq,
    const float* __restrict__ wk, const float* __restrict__ wv,
    const float* __restrict__ wo,
    u16* __restrict__ xb, u16* __restrict__ wqb, u16* __restrict__ wkb,
    u16* __restrict__ wvb, u16* __restrict__ wob) {
  long i4 = (long)blockIdx.x * 256 + threadIdx.x;   // float4 index, < 2097152
  const float* src; u16* dst; long rel;
  if (i4 < 1048576) { src = x; dst = xb; rel = i4; }
  else {
    long j = i4 - 1048576;
    int w = (int)(j >> 18);          // 262144 float4 per weight
    rel = j & 262143;
    src = (w == 0) ? wq : (w == 1) ? wk : (w == 2) ? wv : wo;
    dst = (w == 0) ? wqb : (w == 1) ? wkb : (w == 2) ? wvb : wob;
  }
  float4 v = ((const float4*)src)[rel];
  ushort4 o;
  o.x = f2bf(v.x); o.y = f2bf(v.y); o.z = f2bf(v.z); o.w = f2bf(v.w);
  ((ushort4*)dst)[rel] = o;
}

// ---------------------------------------------------------------- fast GEMM (bf16 in)
// C = A @ B^T + bias. 128x128 tile, BK=64, 4 waves 2x2 each 64x64 (4x4 MFMA 16x16x32).
// m97 structure: global_load_lds width=16 staging. blockIdx.y selects output segment.
template <bool STORE_BF16>
__global__ __launch_bounds__(256) void gemm_fast(
    const u16* __restrict__ A,
    const u16* __restrict__ B0, const u16* __restrict__ B1, const u16* __restrict__ B2,
    const float* __restrict__ b0, const float* __restrict__ b1,
    const float* __restrict__ b2,
    void* __restrict__ C0, void* __restrict__ C1, void* __restrict__ C2) {
  constexpr int K = 1024;
  __shared__ __align__(16) u16 As[128 * 64];
  __shared__ __align__(16) u16 Bs[128 * 64];

  const int m0 = blockIdx.x * 128;
  const int sel = blockIdx.y >> 3;
  const int nloc = (blockIdx.y & 7) * 128;
  const u16* B = sel == 0 ? B0 : sel == 1 ? B1 : B2;
  const float* bias = sel == 0 ? b0 : sel == 1 ? b1 : b2;
  void* Cout = sel == 0 ? C0 : sel == 1 ? C1 : C2;

  const int t = threadIdx.x;
  const int lane = t & 63;
  const int wv = t >> 6;
  const int quad = lane >> 4;
  const int l15 = lane & 15;
  const int wr = wv >> 1, wc = wv & 1;

  const f32x4 vzero = {0.f, 0.f, 0.f, 0.f};
  f32x4 acc[4][4];
#pragma unroll
  for (int i = 0; i < 4; ++i)
#pragma unroll
    for (int j = 0; j < 4; ++j) acc[i][j] = vzero;

  for (int kt = 0; kt < K / 64; ++kt) {
    const int k0 = kt * 64;
#pragma unroll
    for (int p = 0; p < 4; ++p) {
      int idx = t + p * 256;          // 1024 16B groups per tile
      int row = idx >> 3, seg = idx & 7;
      gl_lds16(&A[(long)(m0 + row) * K + k0 + seg * 8], &As[idx * 8]);
      gl_lds16(&B[(long)(nloc + row) * K + k0 + seg * 8], &Bs[idx * 8]);
    }
    __syncthreads();
#pragma unroll
    for (int ks = 0; ks < 64; ks += 32) {
      bf16x8 af[4], bfg[4];
#pragma unroll
      for (int i = 0; i < 4; ++i)
        af[i] = *(const bf16x8*)&As[(wr * 64 + i * 16 + l15) * 64 + ks + quad * 8];
#pragma unroll
      for (int j = 0; j < 4; ++j)
        bfg[j] = *(const bf16x8*)&Bs[(wc * 64 + j * 16 + l15) * 64 + ks + quad * 8];
#pragma unroll
      for (int i = 0; i < 4; ++i)
#pragma unroll
        for (int j = 0; j < 4; ++j)
          acc[i][j] = __builtin_amdgcn_mfma_f32_16x16x32_bf16(af[i], bfg[j], acc[i][j], 0, 0, 0);
    }
    __syncthreads();
  }

  float bv[4];
#pragma unroll
  for (int j = 0; j < 4; ++j) bv[j] = bias[nloc + wc * 64 + j * 16 + l15];

#pragma unroll
  for (int i = 0; i < 4; ++i) {
#pragma unroll
    for (int r = 0; r < 4; ++r) {
      int row = m0 + wr * 64 + i * 16 + quad * 4 + r;
      long base = (long)row * 1024 + nloc + wc * 64;
#pragma unroll
      for (int j = 0; j < 4; ++j) {
        float v = acc[i][j][r] + bv[j];
        if (STORE_BF16) ((u16*)Cout)[base + j * 16 + l15] = f2bf(v);
        else            ((float*)Cout)[base + j * 16 + l15] = v;
      }
    }
  }
}

// ---------------------------------------------------------------- fallback GEMM (fp32 in)
// Round-2 kernel, unchanged (known-good). Used only if ws_size < 24MB.
template <bool A_BF16, bool STORE_BF16>
__global__ __launch_bounds__(256) void gemm_bt(
    const void* __restrict__ A_,
    const float* __restrict__ B0f, const float* __restrict__ B1f,
    const float* __restrict__ B2f,
    const float* __restrict__ b0, const float* __restrict__ b1,
    const float* __restrict__ b2,
    void* __restrict__ C0, void* __restrict__ C1, void* __restrict__ C2) {
  constexpr int K = 1024;
  __shared__ __align__(16) u16 As[128 * 64];
  __shared__ __align__(16) u16 Bs[128 * 64];

  const int m0 = blockIdx.x * 128;
  const int sel = blockIdx.y >> 3;
  const int nloc = (blockIdx.y & 7) * 128;
  const float* Bf = sel == 0 ? B0f : sel == 1 ? B1f : B2f;
  const float* bias = sel == 0 ? b0 : sel == 1 ? b1 : b2;
  void* Cout = sel == 0 ? C0 : sel == 1 ? C1 : C2;

  const int t = threadIdx.x;
  const int lane = t & 63;
  const int wv = t >> 6;
  const int quad = lane >> 4;
  const int l15 = lane & 15;
  const int wr = wv >> 1, wc = wv & 1;

  const f32x4 vzero = {0.f, 0.f, 0.f, 0.f};
  f32x4 acc[4][4];
#pragma unroll
  for (int i = 0; i < 4; ++i)
#pragma unroll
    for (int j = 0; j < 4; ++j) acc[i][j] = vzero;

  for (int kt = 0; kt < K / 64; ++kt) {
    const int k0 = kt * 64;
#pragma unroll
    for (int p = 0; p < 4; ++p) {
      int idx = t + p * 256;
      int row = idx >> 3, c8 = idx & 7;
      if (A_BF16) {
        *(bf16x8*)&As[idx * 8] =
            *(const bf16x8*)&((const u16*)A_)[(long)(m0 + row) * K + k0 + c8 * 8];
      } else {
        const float* A = (const float*)A_;
        float4 a = *(const float4*)&A[(long)(m0 + row) * K + k0 + c8 * 8];
        float4 b = *(const float4*)&A[(long)(m0 + row) * K + k0 + c8 * 8 + 4];
        *(bf16x8*)&As[idx * 8] = pack8(a, b);
      }
      float4 ba = *(const float4*)&Bf[(long)(nloc + row) * K + k0 + c8 * 8];
      float4 bb = *(const float4*)&Bf[(long)(nloc + row) * K + k0 + c8 * 8 + 4];
      *(bf16x8*)&Bs[idx * 8] = pack8(ba, bb);
    }
    __syncthreads();
#pragma unroll
    for (int ks = 0; ks < 64; ks += 32) {
      bf16x8 af[4], bfg[4];
#pragma unroll
      for (int i = 0; i < 4; ++i)
        af[i] = *(const bf16x8*)&As[(wr * 64 + i * 16 + l15) * 64 + ks + quad * 8];
#pragma unroll
      for (int j = 0; j < 4; ++j)
        bfg[j] = *(const bf16x8*)&Bs[(wc * 64 + j * 16 + l15) * 64 + ks + quad * 8];
#pragma unroll
      for (int i = 0; i < 4; ++i)
#pragma unroll
        for (int j = 0; j < 4; ++j)
          acc[i][j] = __builtin_amdgcn_mfma_f32_16x16x32_bf16(af[i], bfg[j], acc[i][j], 0, 0, 0);
    }
    __syncthreads();
  }

  float bv[4];
#pragma unroll
  for (int j = 0; j < 4; ++j) bv[j] = bias[nloc + wc * 64 + j * 16 + l15];

#pragma unroll
  for (int i = 0; i < 4; ++i) {
#pragma unroll
    for (int r = 0; r < 4; ++r) {
      int row = m0 + wr * 64 + i * 16 + quad * 4 + r;
      long base = (long)row * 1024 + nloc + wc * 64;
#pragma unroll
      for (int j = 0; j < 4; ++j) {
        float v = acc[i][j][r] + bv[j];
        if (STORE_BF16) ((u16*)Cout)[base + j * 16 + l15] = f2bf(v);
        else            ((float*)Cout)[base + j * 16 + l15] = v;
      }
    }
  }
}

// ---------------------------------------------------------------- attention
// One block = (b, h, 64 q-rows). 4 waves, wave wv owns q rows q0+wv*16..+15.
// Flash-style loop over causal 64-wide k-chunks; relu weights (no max-tracking needed).
// K staged via global_load_lds; V transposed through registers (gl_lds can't scatter).
// W: C-layout -> bf16 -> wave-private LDS -> A-layout reload (m120 transform).
// In-place output over this block's own Q region (disjoint, read-before-write).
__global__ __launch_bounds__(256) void attn_kernel(
    const u16* __restrict__ Qb,     // [4096][1024], also output (att)
    const u16* __restrict__ Kb,     // [4096][1024]
    const u16* __restrict__ Vb,     // [4096][1024]
    const float* __restrict__ rel_bias,  // [63][16]
    u16* __restrict__ att) {
  __shared__ __align__(16) u16 Ks[64 * 64];
  __shared__ __align__(16) u16 Vt[64 * 72];
  __shared__ __align__(16) u16 Ws[4][16 * 64];
  __shared__ float biasl[64];

  const int bx = blockIdx.x;
  const int qb = bx & 15;
  const int bh = bx >> 4;
  const int b = bh >> 4, h = bh & 15;
  const int q0 = qb * 64;

  const int t = threadIdx.x;
  const int lane = t & 63;
  const int wv = t >> 6;
  const int quad = lane >> 4;
  const int l15 = lane & 15;

  if (t < 63) biasl[t] = rel_bias[t * 16 + h];

  const long qrow = (long)(b * 1024 + q0 + wv * 16 + l15) * 1024 + h * 64;
  bf16x8 qf0 = *(const bf16x8*)&Qb[qrow + quad * 8];
  bf16x8 qf1 = *(const bf16x8*)&Qb[qrow + 32 + quad * 8];

  const f32x4 vzero = {0.f, 0.f, 0.f, 0.f};
  f32x4 acc_o[4];
#pragma unroll
  for (int j = 0; j < 4; ++j) acc_o[j] = vzero;
  f32x4 denom = vzero;
  const float scale = 0.125f;  // 64^-0.5
  const int myq = q0 + wv * 16 + quad * 4;

  for (int c = 0; c <= qb; ++c) {
    const int k0 = c * 64;
    if (c) __syncthreads();  // protect Ks/Vt reuse across iterations
    // stage K rows [k0..k0+63] x 64 head-cols via global_load_lds (16B/lane)
#pragma unroll
    for (int p = 0; p < 2; ++p) {
      int idx = t + p * 256;
      int row = idx >> 3, seg = idx & 7;
      gl_lds16(&Kb[(long)(b * 1024 + k0 + row) * 1024 + h * 64 + seg * 8], &Ks[idx * 8]);
    }
    // stage V transposed: Vt[d][k] = V[k0+k][h*64+d], row stride 72
#pragma unroll
    for (int p = 0; p < 2; ++p) {
      int seg = lane >> 3;
      int krel = (lane & 7) + (p * 4 + wv) * 8;
      uint4 vvld = *(const uint4*)&Vb[(long)(b * 1024 + k0 + krel) * 1024 + h * 64 + seg * 8];
      const u16* u = (const u16*)&vvld;
#pragma unroll
      for (int j = 0; j < 8; ++j) Vt[(seg * 8 + j) * 72 + krel] = u[j];
    }
    __syncthreads();

    // S tiles + weight transform
#pragma unroll
    for (int g = 0; g < 4; ++g) {
      bf16x8 kf0 = *(const bf16x8*)&Ks[(g * 16 + l15) * 64 + quad * 8];
      bf16x8 kf1 = *(const bf16x8*)&Ks[(g * 16 + l15) * 64 + 32 + quad * 8];
      f32x4 s = vzero;
      s = __builtin_amdgcn_mfma_f32_16x16x32_bf16(qf0, kf0, s, 0, 0, 0);
      s = __builtin_amdgcn_mfma_f32_16x16x32_bf16(qf1, kf1, s, 0, 0, 0);
      const int kg = k0 + g * 16 + l15;
#pragma unroll
      for (int r = 0; r < 4; ++r) {
        int q = myq + r;
        int dd = kg - q;
        dd = dd < -31 ? -31 : (dd > 31 ? 31 : dd);
        float sv = s[r] * scale + biasl[dd + 31];
        float w = (kg <= q) ? (fmaxf(sv, 0.f) + 1e-6f) : 0.f;
        u16 wb = f2bf(w);
        denom[r] += bf2f(wb);  // accumulate exactly what PV will consume
        Ws[wv][(quad * 4 + r) * 64 + g * 16 + l15] = wb;
      }
    }
    // intra-wave LDS write->read ordering (Ws[wv] is wave-private)
    asm volatile("s_waitcnt lgkmcnt(0)" ::: "memory");
    // PV: O[q, d] += W[q, k] * V[k, d]
#pragma unroll
    for (int ks = 0; ks < 64; ks += 32) {
      bf16x8 aw = *(const bf16x8*)&Ws[wv][l15 * 64 + ks + quad * 8];
#pragma unroll
      for (int j = 0; j < 4; ++j) {
        bf16x8 bvv = *(const bf16x8*)&Vt[(j * 16 + l15) * 72 + ks + quad * 8];
        acc_o[j] = __builtin_amdgcn_mfma_f32_16x16x32_bf16(aw, bvv, acc_o[j], 0, 0, 0);
      }
    }
  }

  // denom: sum across the 16 lanes of each quad (key-columns of the C-tile)
#pragma unroll
  for (int m = 1; m < 16; m <<= 1)
#pragma unroll
    for (int r = 0; r < 4; ++r) denom[r] += __shfl_xor(denom[r], m);

  float inv[4];
#pragma unroll
  for (int r = 0; r < 4; ++r) inv[r] = 1.f / (denom[r] + 1e-6f);

#pragma unroll
  for (int j = 0; j < 4; ++j)
#pragma unroll
    for (int r = 0; r < 4; ++r) {
      int q = myq + r;
      att[(long)(b * 1024 + q) * 1024 + h * 64 + j * 16 + l15] = f2bf(acc_o[j][r] * inv[r]);
    }
}

// ---------------------------------------------------------------- launch
extern "C" void kernel_launch(void* const* d_in, const int* in_sizes, int n_in,
                              void* d_out, int out_size, void* d_ws, size_t ws_size,
                              hipStream_t stream) {
  const float* x  = (const float*)d_in[0];
  // d_in[1] = mask (causal tril, known analytically -> unused)
  const float* Wq = (const float*)d_in[2];
  const float* bq = (const float*)d_in[3];
  const float* Wk = (const float*)d_in[4];
  const float* bk = (const float*)d_in[5];
  const float* Wv = (const float*)d_in[6];
  const float* bv = (const float*)d_in[7];
  const float* Wo = (const float*)d_in[8];
  const float* bo = (const float*)d_in[9];
  const float* rb = (const float*)d_in[10];
  // d_in[11] = n_head (constant 16) unused

  u16* Kb = (u16*)d_out;                         // 8MB scratch inside d_out
  u16* Vb = (u16*)((char*)d_out + (8l << 20));   // 8MB scratch inside d_out

  if (ws_size >= (24u << 20)) {
    // fast path: pre-cast + global_load_lds GEMMs
    char* ws = (char*)d_ws;
    u16* xb  = (u16*)(ws);
    u16* wqb = (u16*)(ws + (8l  << 20));
    u16* wkb = (u16*)(ws + (10l << 20));
    u16* wvb = (u16*)(ws + (12l << 20));
    u16* wob = (u16*)(ws + (14l << 20));
    u16* Qb  = (u16*)(ws + (16l << 20));

    cast_all_kernel<<<8192, 256, 0, stream>>>(x, Wq, Wk, Wv, Wo, xb, wqb, wkb, wvb, wob);
    gemm_fast<true><<<dim3(32, 24), 256, 0, stream>>>(
        xb, wqb, wkb, wvb, bq, bk, bv, Qb, Kb, Vb);
    attn_kernel<<<1024, 256, 0, stream>>>(Qb, Kb, Vb, rb, Qb);
    gemm_fast<false><<<dim3(32, 8), 256, 0, stream>>>(
        Qb, wob, wob, wob, bo, bo, bo, d_out, d_out, d_out);
  } else {
    // fallback: round-2 known-good path (8MB ws)
    u16* Qb = (u16*)d_ws;
    gemm_bt<false, true><<<dim3(32, 24), 256, 0, stream>>>(
        x, Wq, Wk, Wv, bq, bk, bv, Qb, Kb, Vb);
    attn_kernel<<<1024, 256, 0, stream>>>(Qb, Kb, Vb, rb, Qb);
    gemm_bt<true, false><<<dim3(32, 8), 256, 0, stream>>>(
        Qb, Wo, Wo, Wo, bo, bo, bo, d_out, d_out, d_out);
  }
}

// Round 4
// 225.838 us; speedup vs baseline: 1.1563x; 1.0498x over previous
//
#include <hip/hip_runtime.h>

// AlgebraicAttention on MI355X (gfx950), round 4.
// R3 post-mortem: attention 70us, Occ 20%, MfmaUtil 4.6% -> causal-tail-bound +
// 9.75M LDS bank-conflict cycles (Vt stride-72 scatter = 8-way). Fix: split-K
// attention (relu weights sum linearly -> trivial partial combine), Vt stride 68.
// ws layout (>=24MB, proven in R3):
//   ws[0,8M)     xb: x bf16 (QKV gemm input); dead after -> Opart (1024 x 4096 u16)
//   ws[8,10M)    wqb; dead after QKV -> Dpart (1024 x 64 f32 = 256KB)
//   ws[10,12M)   wkb   ws[12,14M) wvb   (dead after QKV)
//   ws[14,16M)   wob   (live until out-proj)
//   ws[16,24M)   Qb: Q bf16 [4096][1024]; attention output written in-place
//   d_out[0,8M)  Kb    d_out[8,16M) Vb  (dead before out-proj writes)

typedef __attribute__((ext_vector_type(8))) __bf16 bf16x8;
typedef __attribute__((ext_vector_type(4))) __bf16 bf16x4;
typedef __attribute__((ext_vector_type(4))) float f32x4;
typedef unsigned short u16;

__device__ __forceinline__ u16 f2bf(float f) {
  unsigned u = __float_as_uint(f);
  u += 0x7FFFu + ((u >> 16) & 1u);   // round-to-nearest-even
  return (u16)(u >> 16);
}
__device__ __forceinline__ float bf2f(u16 b) {
  return __uint_as_float(((unsigned)b) << 16);
}
__device__ __forceinline__ void gl_lds16(const void* g, void* l) {
  __builtin_amdgcn_global_load_lds((__attribute__((address_space(1))) void*)g,
                                   (__attribute__((address_space(3))) void*)l,
                                   16, 0, 0);
}

// ---------------------------------------------------------------- cast kernel
__global__ __launch_bounds__(256) void cast_all_kernel(
    const float* __restrict__ x,  const float* __restrict__ wq,
    const float* __restrict__ wk, const float* __restrict__ wv,
    const float* __restrict__ wo,
    u16* __restrict__ xb, u16* __restrict__ wqb, u16* __restrict__ wkb,
    u16* __restrict__ wvb, u16* __restrict__ wob) {
  long i4 = (long)blockIdx.x * 256 + threadIdx.x;   // float4 index, < 2097152
  const float* src; u16* dst; long rel;
  if (i4 < 1048576) { src = x; dst = xb; rel = i4; }
  else {
    long j = i4 - 1048576;
    int w = (int)(j >> 18);          // 262144 float4 per weight
    rel = j & 262143;
    src = (w == 0) ? wq : (w == 1) ? wk : (w == 2) ? wv : wo;
    dst = (w == 0) ? wqb : (w == 1) ? wkb : (w == 2) ? wvb : wob;
  }
  float4 v = ((const float4*)src)[rel];
  ushort4 o;
  o.x = f2bf(v.x); o.y = f2bf(v.y); o.z = f2bf(v.z); o.w = f2bf(v.w);
  ((ushort4*)dst)[rel] = o;
}

// ---------------------------------------------------------------- GEMM (bf16 in)
// C = A @ B^T + bias, m97 structure (global_load_lds width=16). 128x128 tile, BK=64.
template <bool STORE_BF16>
__global__ __launch_bounds__(256) void gemm_fast(
    const u16* __restrict__ A,
    const u16* __restrict__ B0, const u16* __restrict__ B1, const u16* __restrict__ B2,
    const float* __restrict__ b0, const float* __restrict__ b1,
    const float* __restrict__ b2,
    void* __restrict__ C0, void* __restrict__ C1, void* __restrict__ C2) {
  constexpr int K = 1024;
  __shared__ __align__(16) u16 As[128 * 64];
  __shared__ __align__(16) u16 Bs[128 * 64];

  const int m0 = blockIdx.x * 128;
  const int sel = blockIdx.y >> 3;
  const int nloc = (blockIdx.y & 7) * 128;
  const u16* B = sel == 0 ? B0 : sel == 1 ? B1 : B2;
  const float* bias = sel == 0 ? b0 : sel == 1 ? b1 : b2;
  void* Cout = sel == 0 ? C0 : sel == 1 ? C1 : C2;

  const int t = threadIdx.x;
  const int lane = t & 63;
  const int wv = t >> 6;
  const int quad = lane >> 4;
  const int l15 = lane & 15;
  const int wr = wv >> 1, wc = wv & 1;

  const f32x4 vzero = {0.f, 0.f, 0.f, 0.f};
  f32x4 acc[4][4];
#pragma unroll
  for (int i = 0; i < 4; ++i)
#pragma unroll
    for (int j = 0; j < 4; ++j) acc[i][j] = vzero;

  for (int kt = 0; kt < K / 64; ++kt) {
    const int k0 = kt * 64;
#pragma unroll
    for (int p = 0; p < 4; ++p) {
      int idx = t + p * 256;
      int row = idx >> 3, seg = idx & 7;
      gl_lds16(&A[(long)(m0 + row) * K + k0 + seg * 8], &As[idx * 8]);
      gl_lds16(&B[(long)(nloc + row) * K + k0 + seg * 8], &Bs[idx * 8]);
    }
    __syncthreads();
#pragma unroll
    for (int ks = 0; ks < 64; ks += 32) {
      bf16x8 af[4], bfg[4];
#pragma unroll
      for (int i = 0; i < 4; ++i)
        af[i] = *(const bf16x8*)&As[(wr * 64 + i * 16 + l15) * 64 + ks + quad * 8];
#pragma unroll
      for (int j = 0; j < 4; ++j)
        bfg[j] = *(const bf16x8*)&Bs[(wc * 64 + j * 16 + l15) * 64 + ks + quad * 8];
#pragma unroll
      for (int i = 0; i < 4; ++i)
#pragma unroll
        for (int j = 0; j < 4; ++j)
          acc[i][j] = __builtin_amdgcn_mfma_f32_16x16x32_bf16(af[i], bfg[j], acc[i][j], 0, 0, 0);
    }
    __syncthreads();
  }

  float bv[4];
#pragma unroll
  for (int j = 0; j < 4; ++j) bv[j] = bias[nloc + wc * 64 + j * 16 + l15];

#pragma unroll
  for (int i = 0; i < 4; ++i) {
#pragma unroll
    for (int r = 0; r < 4; ++r) {
      int row = m0 + wr * 64 + i * 16 + quad * 4 + r;
      long base = (long)row * 1024 + nloc + wc * 64;
#pragma unroll
      for (int j = 0; j < 4; ++j) {
        float v = acc[i][j][r] + bv[j];
        if (STORE_BF16) ((u16*)Cout)[base + j * 16 + l15] = f2bf(v);
        else            ((float*)Cout)[base + j * 16 + l15] = v;
      }
    }
  }
}

// ---------------------------------------------------------------- attention (split-K)
// Block slot layout per (b,h): slot 0..7  = qb=slot, chunks [0,qb], direct output.
//                              slot 8..23 = qb=8+((slot-8)>>1), part=(slot-8)&1:
//                                part0 chunks [0,7], part1 chunks [8,qb] -> partials.
// Per chunk: S=QK^T (MFMA) -> relu(scale*S+relbias)+1e-6 masked -> bf16 -> wave-private
// LDS -> A-layout reload -> PV MFMA (V transposed in LDS, stride 68 to cut write
// conflicts 8-way -> 4-way; PV B-frags read as 2x b64).
__global__ __launch_bounds__(256) void attn_split(
    const u16* __restrict__ Qb,     // [4096][1024]
    const u16* __restrict__ Kb,     // [4096][1024]
    const u16* __restrict__ Vb,     // [4096][1024]
    const float* __restrict__ rel_bias,  // [63][16]
    u16* __restrict__ att,          // == Qb (in-place; disjoint rows)
    u16* __restrict__ Opart,        // [1024][64][64] bf16 unnormalized partial O
    float* __restrict__ Dpart) {    // [1024][64] partial denominators
  constexpr int VS = 68;            // Vt row stride (u16): 136B, not 0 mod 128B
  __shared__ __align__(16) u16 Ks[64 * 64];
  __shared__ __align__(16) u16 Vt[64 * VS];
  __shared__ __align__(16) u16 Ws[4][16 * 64];
  __shared__ float biasl[64];

  const int bx = blockIdx.x;
  const int bh = bx / 24;
  const int slot = bx - bh * 24;
  const int b = bh >> 4, h = bh & 15;

  int qb, cbeg, cend, pidx;
  bool multi;
  if (slot < 8) { qb = slot; cbeg = 0; cend = qb; multi = false; pidx = 0; }
  else {
    int s = slot - 8;
    qb = 8 + (s >> 1);
    int part = s & 1;
    multi = true;
    pidx = (bh * 8 + (qb - 8)) * 2 + part;
    if (part == 0) { cbeg = 0; cend = 7; }
    else           { cbeg = 8; cend = qb; }
  }
  const int q0 = qb * 64;

  const int t = threadIdx.x;
  const int lane = t & 63;
  const int wv = t >> 6;
  const int quad = lane >> 4;
  const int l15 = lane & 15;

  if (t < 63) biasl[t] = rel_bias[t * 16 + h];

  // Q fragments (A-layout) for this wave's 16 q-rows
  const long qrow = (long)(b * 1024 + q0 + wv * 16 + l15) * 1024 + h * 64;
  bf16x8 qf0 = *(const bf16x8*)&Qb[qrow + quad * 8];
  bf16x8 qf1 = *(const bf16x8*)&Qb[qrow + 32 + quad * 8];

  const f32x4 vzero = {0.f, 0.f, 0.f, 0.f};
  f32x4 acc_o[4];
#pragma unroll
  for (int j = 0; j < 4; ++j) acc_o[j] = vzero;
  f32x4 denom = vzero;
  const float scale = 0.125f;  // 64^-0.5
  const int myq = q0 + wv * 16 + quad * 4;

  for (int c = cbeg; c <= cend; ++c) {
    const int k0 = c * 64;
    if (c != cbeg) __syncthreads();
    // stage K chunk via global_load_lds (16B/lane)
#pragma unroll
    for (int p = 0; p < 2; ++p) {
      int idx = t + p * 256;
      int row = idx >> 3, seg = idx & 7;
      gl_lds16(&Kb[(long)(b * 1024 + k0 + row) * 1024 + h * 64 + seg * 8], &Ks[idx * 8]);
    }
    // stage V transposed: Vt[d][k], row stride 68
#pragma unroll
    for (int p = 0; p < 2; ++p) {
      int seg = lane >> 3;
      int krel = (lane & 7) + (p * 4 + wv) * 8;
      uint4 vvld = *(const uint4*)&Vb[(long)(b * 1024 + k0 + krel) * 1024 + h * 64 + seg * 8];
      const u16* u = (const u16*)&vvld;
#pragma unroll
      for (int j = 0; j < 8; ++j) Vt[(seg * 8 + j) * VS + krel] = u[j];
    }
    __syncthreads();

    // S tiles + weight transform
#pragma unroll
    for (int g = 0; g < 4; ++g) {
      bf16x8 kf0 = *(const bf16x8*)&Ks[(g * 16 + l15) * 64 + quad * 8];
      bf16x8 kf1 = *(const bf16x8*)&Ks[(g * 16 + l15) * 64 + 32 + quad * 8];
      f32x4 s = vzero;
      s = __builtin_amdgcn_mfma_f32_16x16x32_bf16(qf0, kf0, s, 0, 0, 0);
      s = __builtin_amdgcn_mfma_f32_16x16x32_bf16(qf1, kf1, s, 0, 0, 0);
      const int kg = k0 + g * 16 + l15;
#pragma unroll
      for (int r = 0; r < 4; ++r) {
        int q = myq + r;
        int dd = kg - q;
        dd = dd < -31 ? -31 : (dd > 31 ? 31 : dd);
        float sv = s[r] * scale + biasl[dd + 31];
        float w = (kg <= q) ? (fmaxf(sv, 0.f) + 1e-6f) : 0.f;
        u16 wb = f2bf(w);
        denom[r] += bf2f(wb);  // accumulate exactly what PV consumes
        Ws[wv][(quad * 4 + r) * 64 + g * 16 + l15] = wb;
      }
    }
    // intra-wave LDS write->read ordering (Ws[wv] is wave-private)
    asm volatile("s_waitcnt lgkmcnt(0)" ::: "memory");
    // PV: O[q,d] += W[q,k] * V[k,d]
#pragma unroll
    for (int ks = 0; ks < 64; ks += 32) {
      bf16x8 aw = *(const bf16x8*)&Ws[wv][l15 * 64 + ks + quad * 8];
#pragma unroll
      for (int j = 0; j < 4; ++j) {
        union { bf16x8 v8; bf16x4 v4[2]; } bu;
        int vbase = (j * 16 + l15) * VS + ks + quad * 8;
        bu.v4[0] = *(const bf16x4*)&Vt[vbase];
        bu.v4[1] = *(const bf16x4*)&Vt[vbase + 4];
        acc_o[j] = __builtin_amdgcn_mfma_f32_16x16x32_bf16(aw, bu.v8, acc_o[j], 0, 0, 0);
      }
    }
  }

  // denom: sum across the 16 key-lanes of each quad
#pragma unroll
  for (int m = 1; m < 16; m <<= 1)
#pragma unroll
    for (int r = 0; r < 4; ++r) denom[r] += __shfl_xor(denom[r], m);

  if (!multi) {
    float inv[4];
#pragma unroll
    for (int r = 0; r < 4; ++r) inv[r] = 1.f / (denom[r] + 1e-6f);
#pragma unroll
    for (int j = 0; j < 4; ++j)
#pragma unroll
      for (int r = 0; r < 4; ++r) {
        int q = myq + r;
        att[(long)(b * 1024 + q) * 1024 + h * 64 + j * 16 + l15] = f2bf(acc_o[j][r] * inv[r]);
      }
  } else {
    const int qrel = wv * 16 + quad * 4;
#pragma unroll
    for (int j = 0; j < 4; ++j)
#pragma unroll
      for (int r = 0; r < 4; ++r)
        Opart[(long)pidx * 4096 + (qrel + r) * 64 + j * 16 + l15] = f2bf(acc_o[j][r]);
    if (l15 == 0) {
#pragma unroll
      for (int r = 0; r < 4; ++r) Dpart[pidx * 64 + qrel + r] = denom[r];
    }
  }
}

// ---------------------------------------------------------------- partial combine
// 512 blocks = (bh, qb-8). out = (O0+O1)/(d0+d1+1e-6) -> att rows of qb>=8.
__global__ __launch_bounds__(256) void attn_reduce(
    const u16* __restrict__ Opart, const float* __restrict__ Dpart,
    u16* __restrict__ att) {
  const int bx = blockIdx.x;
  const int bh = bx >> 3;
  const int q8 = bx & 7;
  const int b = bh >> 4, h = bh & 15;
  const int qb = 8 + q8;
  const int pidx = (bh * 8 + q8) * 2;

  const int t = threadIdx.x;
  const int row = t >> 2;
  const int dseg = t & 3;

  const float d0 = Dpart[pidx * 64 + row];
  const float d1 = Dpart[(pidx + 1) * 64 + row];
  const float inv = 1.f / (d0 + d1 + 1e-6f);

  const u16* O0 = Opart + (long)pidx * 4096 + row * 64 + dseg * 16;
  const u16* O1 = O0 + 4096;
  union { uint4 q[2]; u16 s[16]; } a, c, o;
  a.q[0] = *(const uint4*)O0;       a.q[1] = *(const uint4*)(O0 + 8);
  c.q[0] = *(const uint4*)O1;       c.q[1] = *(const uint4*)(O1 + 8);
#pragma unroll
  for (int i = 0; i < 16; ++i) o.s[i] = f2bf((bf2f(a.s[i]) + bf2f(c.s[i])) * inv);
  u16* dst = att + (long)(b * 1024 + qb * 64 + row) * 1024 + h * 64 + dseg * 16;
  *(uint4*)dst = o.q[0];
  *(uint4*)(dst + 8) = o.q[1];
}

// ---------------------------------------------------------------- launch
extern "C" void kernel_launch(void* const* d_in, const int* in_sizes, int n_in,
                              void* d_out, int out_size, void* d_ws, size_t ws_size,
                              hipStream_t stream) {
  const float* x  = (const float*)d_in[0];
  const float* Wq = (const float*)d_in[2];
  const float* bq = (const float*)d_in[3];
  const float* Wk = (const float*)d_in[4];
  const float* bk = (const float*)d_in[5];
  const float* Wv = (const float*)d_in[6];
  const float* bv = (const float*)d_in[7];
  const float* Wo = (const float*)d_in[8];
  const float* bo = (const float*)d_in[9];
  const float* rb = (const float*)d_in[10];

  char* ws = (char*)d_ws;
  u16* xb    = (u16*)(ws);                       // dead after QKV ->
  u16* Opart = (u16*)(ws);                       //   partial O (8MB)
  u16* wqb   = (u16*)(ws + (8l  << 20));         // dead after QKV ->
  float* Dpart = (float*)(ws + (8l << 20));      //   partial denom (256KB)
  u16* wkb   = (u16*)(ws + (10l << 20));
  u16* wvb   = (u16*)(ws + (12l << 20));
  u16* wob   = (u16*)(ws + (14l << 20));
  u16* Qb    = (u16*)(ws + (16l << 20));
  u16* Kb    = (u16*)d_out;
  u16* Vb    = (u16*)((char*)d_out + (8l << 20));

  cast_all_kernel<<<8192, 256, 0, stream>>>(x, Wq, Wk, Wv, Wo, xb, wqb, wkb, wvb, wob);
  gemm_fast<true><<<dim3(32, 24), 256, 0, stream>>>(
      xb, wqb, wkb, wvb, bq, bk, bv, Qb, Kb, Vb);
  attn_split<<<1536, 256, 0, stream>>>(Qb, Kb, Vb, rb, Qb, Opart, Dpart);
  attn_reduce<<<512, 256, 0, stream>>>(Opart, Dpart, Qb);
  gemm_fast<false><<<dim3(32, 8), 256, 0, stream>>>(
      Qb, wob, wob, wob, bo, bo, bo, d_out, d_out, d_out);
}